// Round 3
// baseline (653.108 us; speedup 1.0000x reference)
//
#include <hip/hip_runtime.h>

#define NN 50000
#define DD 64
#define EE 800000
#define BB 50
#define NMAXX 1000
#define CC 100

typedef short short8 __attribute__((ext_vector_type(8)));
typedef float float4v __attribute__((ext_vector_type(4)));

__device__ __forceinline__ float rl(float v, int l) {
  return __int_as_float(__builtin_amdgcn_readlane(__float_as_int(v), l));
}
__device__ __forceinline__ short f2bf(float f) {
  unsigned u = __float_as_uint(f);
  unsigned r = (u + 0x7fffu + ((u >> 16) & 1u)) >> 16;
  return (short)r;
}
__device__ __forceinline__ unsigned pack2(float a, float b) {
  return (unsigned)(unsigned short)f2bf(a) |
         ((unsigned)(unsigned short)f2bf(b) << 16);
}

// ---------- counting sort of edges by dst ----------
__global__ __launch_bounds__(256) void k_hist(const int* __restrict__ ei,
                                              int* __restrict__ cnt) {
  int i = blockIdx.x * 256 + threadIdx.x;
  atomicAdd(&cnt[ei[EE + i]], 1);
}

__global__ __launch_bounds__(256) void k_scan(const int* __restrict__ cnt,
                                              int* __restrict__ head) {
  __shared__ int part[256];
  __shared__ int partx[256];
  const int t = threadIdx.x;
  const int chunk = (NN + 255) / 256;      // 196
  const int c0 = t * chunk;
  const int c1 = min(c0 + chunk, NN);
  int s = 0;
  for (int i = c0; i < c1; ++i) s += cnt[i];
  part[t] = s;
  __syncthreads();
  if (t == 0) {
    int r = 0;
    for (int i = 0; i < 256; ++i) { partx[i] = r; r += part[i]; }
  }
  __syncthreads();
  int run = partx[t];
  for (int i = c0; i < c1; ++i) { head[i] = run; run += cnt[i]; }
}

__global__ __launch_bounds__(256) void k_scatter(const int* __restrict__ ei,
                                                 int* __restrict__ head,
                                                 int* __restrict__ perm,
                                                 int* __restrict__ srcS,
                                                 int* __restrict__ dstS) {
  int i = blockIdx.x * 256 + threadIdx.x;
  int d = ei[EE + i];
  int pos = atomicAdd(&head[d], 1);
  perm[pos] = i;
  srcS[pos] = ei[i];
  dstS[pos] = d;
}

// ---------- K1: msg_up = relu(attr1 @ W_mu + b_mu), rows = B*C = 5000 ----------
__global__ __launch_bounds__(256) void k_msgup(
    const float* __restrict__ attr1, const float* __restrict__ Wmu,
    const float* __restrict__ bmu, float* __restrict__ msgup) {
  __shared__ float Wl[64 * 64];
  const int tid = threadIdx.x;
  for (int i = tid; i < 64 * 64; i += 256) Wl[i] = Wmu[i];
  __syncthreads();
  const int lane = tid & 63;
  const int row = blockIdx.x * 4 + (tid >> 6);
  float a = attr1[(size_t)row * 64 + lane];
  float acc = bmu[lane];
#pragma unroll 8
  for (int k = 0; k < 64; ++k)
    acc = fmaf(rl(a, k), Wl[k * 64 + lane], acc);
  msgup[(size_t)row * 64 + lane] = fmaxf(acc, 0.f);
}

// ---------- K2 (MFMA): agg_up[b,i,:] = sum_c nc1[b,i,c] * msg_up[b,c,:] ----------
// grid (b,tile): 64 rows per block; K = 100 zero-padded to 128.
__global__ __launch_bounds__(256) void k_aggup(
    const float* __restrict__ nc1, const float* __restrict__ msgup,
    float* __restrict__ aggup) {
  constexpr int LDA = 136;
  __shared__ float Ncf[64 * CC];      // 25.6 KB raw f32 tile
  __shared__ short A[64 * LDA];       // 17.4 KB bf16 A (K-padded)
  __shared__ short Wt[64 * LDA];      // 17.4 KB bf16 B: Wt[d][c] = msgup[b][c][d]
  const int b = blockIdx.x >> 4;
  const int tile = blockIdx.x & 15;
  const int i0 = tile * 64;
  const int tid = threadIdx.x;
  // stage nc1 tile (coalesced, clamp rows >= NMAXX to 0)
  const float* ncb = nc1 + ((size_t)b * NMAXX + i0) * CC;
  for (int idx = tid; idx < 64 * CC; idx += 256) {
    int r = idx / CC;
    Ncf[idx] = (i0 + r < NMAXX) ? ncb[idx] : 0.f;
  }
  // stage msgup[b] transposed as bf16, zero the K-pad first
  for (int i = tid; i < 64 * LDA; i += 256) Wt[i] = 0;
  __syncthreads();
  for (int idx = tid; idx < CC * 64; idx += 256) {
    int c = idx >> 6, d = idx & 63;
    Wt[d * LDA + c] = f2bf(msgup[(size_t)b * CC * 64 + idx]);
  }
  __syncthreads();
  // pack A rows bf16 from Ncf
  {
    const int row = tid >> 2, kp = tid & 3;
#pragma unroll
    for (int j = 0; j < 16; ++j) {
      int k = kp * 32 + 2 * j;
      unsigned u = 0;
      if (k < CC) {
        float2 v = *(const float2*)&Ncf[row * CC + k];
        u = pack2(v.x, v.y);
      }
      *(unsigned*)&A[row * LDA + k] = u;
    }
  }
  __syncthreads();
  const int lane = tid & 63;
  const int w = tid >> 6;
  const int m = lane & 15;
  const int koff = (lane >> 4) * 8;
  float4v acc[4];
#pragma unroll
  for (int cb = 0; cb < 4; ++cb) acc[cb] = (float4v)0.f;
#pragma unroll
  for (int ks = 0; ks < 4; ++ks) {
    short8 af = *(const short8*)&A[(w * 16 + m) * LDA + ks * 32 + koff];
#pragma unroll
    for (int cb = 0; cb < 4; ++cb) {
      short8 bf = *(const short8*)&Wt[(cb * 16 + m) * LDA + ks * 32 + koff];
      acc[cb] = __builtin_amdgcn_mfma_f32_16x16x32_bf16(af, bf, acc[cb], 0, 0, 0);
    }
  }
  const int rbase = (lane >> 4) * 4;
#pragma unroll
  for (int cb = 0; cb < 4; ++cb)
#pragma unroll
    for (int r = 0; r < 4; ++r) {
      int i = i0 + w * 16 + rbase + r;
      if (i < NMAXX)
        aggup[((size_t)b * NMAXX + i) * 64 + cb * 16 + m] = acc[cb][r];
    }
}

// ---------- K3 (MFMA, dst-sorted): edge MLP + segmented scatter ----------
__global__ __launch_bounds__(256) void k_edge_mfma(
    const float* __restrict__ x, const float* __restrict__ e,
    const int* __restrict__ perm, const int* __restrict__ srcS,
    const int* __restrict__ dstSg, const float* __restrict__ Wma,
    const float* __restrict__ bma, float* __restrict__ agg) {
  constexpr int LDA = 136;
  __shared__ short A[64 * LDA];       // 17408 B, aliased by Cs after MFMA
  __shared__ short Wt[64 * LDA];
  __shared__ int dstS[64];
  const int tid = threadIdx.x;
  for (int idx = tid; idx < 128 * 64; idx += 256) {
    int k = idx >> 6, n = idx & 63;
    Wt[n * LDA + k] = f2bf(Wma[idx]);
  }
  const int p0 = blockIdx.x * 64;
  {
    const int edge = tid >> 2;
    const int part = tid & 3;
    const int p = p0 + edge;
    if (part == 0) dstS[edge] = dstSg[p];
    const float* srcp;
    if (part < 2) {
      srcp = x + (size_t)srcS[p] * 64 + part * 32;
    } else {
      srcp = e + (size_t)perm[p] * 64 + (part - 2) * 32;
    }
    unsigned* dstA = (unsigned*)(A + edge * LDA + part * 32);
#pragma unroll
    for (int j = 0; j < 8; ++j) {
      float4 v = ((const float4*)srcp)[j];
      ((uint2*)dstA)[j] = make_uint2(pack2(v.x, v.y), pack2(v.z, v.w));
    }
  }
  __syncthreads();
  const int lane = tid & 63;
  const int w = tid >> 6;
  const int m = lane & 15;
  const int koff = (lane >> 4) * 8;
  float4v acc[4];
#pragma unroll
  for (int cb = 0; cb < 4; ++cb) acc[cb] = (float4v)0.f;
#pragma unroll
  for (int ks = 0; ks < 4; ++ks) {
    short8 af = *(const short8*)&A[(w * 16 + m) * LDA + ks * 32 + koff];
#pragma unroll
    for (int cb = 0; cb < 4; ++cb) {
      short8 bf = *(const short8*)&Wt[(cb * 16 + m) * LDA + ks * 32 + koff];
      acc[cb] = __builtin_amdgcn_mfma_f32_16x16x32_bf16(af, bf, acc[cb], 0, 0, 0);
    }
  }
  __syncthreads();                    // all A/Wt reads done before aliasing
  float* Cs = (float*)A;              // 64 x 68 f32 = 17408 B
  const int rbase = (lane >> 4) * 4;
#pragma unroll
  for (int cb = 0; cb < 4; ++cb) {
    float bias = bma[cb * 16 + m];
#pragma unroll
    for (int r = 0; r < 4; ++r)
      Cs[(w * 16 + rbase + r) * 68 + cb * 16 + m] = fmaxf(acc[cb][r] + bias, 0.f);
  }
  __syncthreads();
  // segmented reduce: thread scans 16 sorted rows of one feature column
  const int col = tid & 63;
  const int r0 = (tid >> 6) * 16;
  int dprev = -1;
  float run = 0.f;
#pragma unroll
  for (int j = 0; j < 16; ++j) {
    int row = r0 + j;
    int d = dstS[row];
    if (d != dprev) {
      if (run != 0.f) atomicAdd(&agg[(size_t)dprev * 64 + col], run);
      run = 0.f;
      dprev = d;
    }
    run += Cs[row * 68 + col];
  }
  if (run != 0.f) atomicAdd(&agg[(size_t)dprev * 64 + col], run);
}

// ---------- K4 (MFMA): fused epilogue, 64 rows/block ----------
__global__ __launch_bounds__(256) void k_final(
    const float* __restrict__ x, const float* __restrict__ agg,
    const float* __restrict__ aggup, const int* __restrict__ xidx,
    const float* __restrict__ eps1, const float* __restrict__ eps2,
    const float* __restrict__ Wua, const float* __restrict__ bua,
    const float* __restrict__ Wuu, const float* __restrict__ buu,
    const float* __restrict__ Wc, const float* __restrict__ bc,
    float* __restrict__ out) {
  constexpr int LD1 = 72;             // K=64 rows
  constexpr int LD3 = 136;            // K=128 rows
  __shared__ short Wt1[64 * LD1];
  __shared__ short Wt2[64 * LD1];
  __shared__ short Wt3[64 * LD3];
  __shared__ short A1[64 * LD1];
  __shared__ short A2[64 * LD1];
  __shared__ short O[64 * LD3];
  const int tid = threadIdx.x;
  for (int idx = tid; idx < 64 * 64; idx += 256) {
    int k = idx >> 6, d = idx & 63;
    Wt1[d * LD1 + k] = f2bf(Wua[idx]);
    Wt2[d * LD1 + k] = f2bf(Wuu[idx]);
  }
  for (int idx = tid; idx < 128 * 64; idx += 256) {
    int k = idx >> 6, d = idx & 63;
    Wt3[d * LD3 + k] = f2bf(Wc[idx]);
  }
  const float s1 = 1.f + eps1[0], s2 = 1.f + eps2[0];
  const int r0 = blockIdx.x * 64;
  {
    const int row = tid >> 2, kp = tid & 3;
    int g = r0 + row;
    if (g >= NN) g = NN - 1;
    const size_t xb = (size_t)g * 64 + kp * 16;
    const size_t ub = (size_t)xidx[g] * 64 + kp * 16;
#pragma unroll
    for (int j = 0; j < 4; ++j) {
      float4 xv = *(const float4*)&x[xb + j * 4];
      float4 av = *(const float4*)&agg[xb + j * 4];
      float4 uv = *(const float4*)&aggup[ub + j * 4];
      unsigned h1lo = pack2(av.x + s1 * xv.x, av.y + s1 * xv.y);
      unsigned h1hi = pack2(av.z + s1 * xv.z, av.w + s1 * xv.w);
      unsigned h2lo = pack2(uv.x + s2 * xv.x, uv.y + s2 * xv.y);
      unsigned h2hi = pack2(uv.z + s2 * xv.z, uv.w + s2 * xv.w);
      *(uint2*)&A1[row * LD1 + kp * 16 + j * 4] = make_uint2(h1lo, h1hi);
      *(uint2*)&A2[row * LD1 + kp * 16 + j * 4] = make_uint2(h2lo, h2hi);
    }
  }
  __syncthreads();
  const int lane = tid & 63;
  const int w = tid >> 6;
  const int m = lane & 15;
  const int koff = (lane >> 4) * 8;
  const int rbase = (lane >> 4) * 4;
  float4v acc1[4], acc2[4];
#pragma unroll
  for (int cb = 0; cb < 4; ++cb) { acc1[cb] = (float4v)0.f; acc2[cb] = (float4v)0.f; }
#pragma unroll
  for (int ks = 0; ks < 2; ++ks) {
    short8 a1 = *(const short8*)&A1[(w * 16 + m) * LD1 + ks * 32 + koff];
    short8 a2 = *(const short8*)&A2[(w * 16 + m) * LD1 + ks * 32 + koff];
#pragma unroll
    for (int cb = 0; cb < 4; ++cb) {
      short8 b1 = *(const short8*)&Wt1[(cb * 16 + m) * LD1 + ks * 32 + koff];
      short8 b2 = *(const short8*)&Wt2[(cb * 16 + m) * LD1 + ks * 32 + koff];
      acc1[cb] = __builtin_amdgcn_mfma_f32_16x16x32_bf16(a1, b1, acc1[cb], 0, 0, 0);
      acc2[cb] = __builtin_amdgcn_mfma_f32_16x16x32_bf16(a2, b2, acc2[cb], 0, 0, 0);
    }
  }
  // relu + write o = [o1 | o2] into O (A-layout for GEMM2)
#pragma unroll
  for (int cb = 0; cb < 4; ++cb) {
    float bb1 = bua[cb * 16 + m];
    float bb2 = buu[cb * 16 + m];
#pragma unroll
    for (int r = 0; r < 4; ++r) {
      int rowL = w * 16 + rbase + r;
      O[rowL * LD3 + cb * 16 + m] = f2bf(fmaxf(acc1[cb][r] + bb1, 0.f));
      O[rowL * LD3 + 64 + cb * 16 + m] = f2bf(fmaxf(acc2[cb][r] + bb2, 0.f));
    }
  }
  __syncthreads();
  float4v acc3[4];
#pragma unroll
  for (int cb = 0; cb < 4; ++cb) acc3[cb] = (float4v)0.f;
#pragma unroll
  for (int ks = 0; ks < 4; ++ks) {
    short8 af = *(const short8*)&O[(w * 16 + m) * LD3 + ks * 32 + koff];
#pragma unroll
    for (int cb = 0; cb < 4; ++cb) {
      short8 bf = *(const short8*)&Wt3[(cb * 16 + m) * LD3 + ks * 32 + koff];
      acc3[cb] = __builtin_amdgcn_mfma_f32_16x16x32_bf16(af, bf, acc3[cb], 0, 0, 0);
    }
  }
#pragma unroll
  for (int cb = 0; cb < 4; ++cb) {
    float bb = bc[cb * 16 + m];
#pragma unroll
    for (int r = 0; r < 4; ++r) {
      int g = r0 + w * 16 + rbase + r;
      if (g < NN)
        out[(size_t)g * 64 + cb * 16 + m] = acc3[cb][r] + bb;
    }
  }
}

extern "C" void kernel_launch(void* const* d_in, const int* in_sizes, int n_in,
                              void* d_out, int out_size, void* d_ws, size_t ws_size,
                              hipStream_t stream) {
  const float* x     = (const float*)d_in[0];
  const float* e     = (const float*)d_in[1];
  const int*   ei    = (const int*)d_in[2];
  const float* attr1 = (const float*)d_in[3];
  const float* nc1   = (const float*)d_in[4];
  const int*   xidx  = (const int*)d_in[5];
  const float* eps1  = (const float*)d_in[6];
  const float* eps2  = (const float*)d_in[7];
  const float* Wma   = (const float*)d_in[8];
  const float* bma   = (const float*)d_in[9];
  const float* Wmu   = (const float*)d_in[10];
  const float* bmu   = (const float*)d_in[11];
  const float* Wua   = (const float*)d_in[12];
  const float* bua   = (const float*)d_in[13];
  const float* Wuu   = (const float*)d_in[14];
  const float* buu   = (const float*)d_in[15];
  const float* Wc    = (const float*)d_in[16];
  const float* bc    = (const float*)d_in[17];
  float* out = (float*)d_out;

  float* agg   = (float*)d_ws;                     // [N,64]
  float* aggup = agg + (size_t)NN * 64;            // [N,64]
  float* msgup = aggup + (size_t)NN * 64;          // [B*C,64]
  int* cnt  = (int*)(msgup + (size_t)BB * CC * 64);
  int* head = cnt + NN;
  int* perm = head + NN;
  int* srcS = perm + EE;
  int* dstS = srcS + EE;

  hipMemsetAsync(agg, 0, (size_t)NN * 64 * sizeof(float), stream);
  hipMemsetAsync(cnt, 0, (size_t)NN * sizeof(int), stream);
  k_hist<<<dim3(EE / 256), dim3(256), 0, stream>>>(ei, cnt);
  k_scan<<<dim3(1), dim3(256), 0, stream>>>(cnt, head);
  k_scatter<<<dim3(EE / 256), dim3(256), 0, stream>>>(ei, head, perm, srcS, dstS);
  k_msgup<<<dim3(BB * CC / 4), dim3(256), 0, stream>>>(attr1, Wmu, bmu, msgup);
  k_aggup<<<dim3(BB * 16), dim3(256), 0, stream>>>(nc1, msgup, aggup);
  k_edge_mfma<<<dim3(EE / 64), dim3(256), 0, stream>>>(x, e, perm, srcS, dstS,
                                                       Wma, bma, agg);
  k_final<<<dim3((NN + 63) / 64), dim3(256), 0, stream>>>(
      x, agg, aggup, xidx, eps1, eps2, Wua, bua, Wuu, buu, Wc, bc, out);
}

// Round 4
// 647.714 us; speedup vs baseline: 1.0083x; 1.0083x over previous
//
#include <hip/hip_runtime.h>

#define NN 50000
#define DD 64
#define EE 800000
#define BB 50
#define NMAXX 1000
#define CC 100

typedef short short8 __attribute__((ext_vector_type(8)));
typedef float float4v __attribute__((ext_vector_type(4)));

__device__ __forceinline__ float rl(float v, int l) {
  return __int_as_float(__builtin_amdgcn_readlane(__float_as_int(v), l));
}
__device__ __forceinline__ short f2bf(float f) {
  unsigned u = __float_as_uint(f);
  unsigned r = (u + 0x7fffu + ((u >> 16) & 1u)) >> 16;
  return (short)r;
}
__device__ __forceinline__ unsigned pack2(float a, float b) {
  return (unsigned)(unsigned short)f2bf(a) |
         ((unsigned)(unsigned short)f2bf(b) << 16);
}
__device__ __forceinline__ short8 pack8(const float* p) {
  union { unsigned u[4]; short8 s; } r;
  float4 v0 = *(const float4*)p;
  float4 v1 = *(const float4*)(p + 4);
  r.u[0] = pack2(v0.x, v0.y); r.u[1] = pack2(v0.z, v0.w);
  r.u[2] = pack2(v1.x, v1.y); r.u[3] = pack2(v1.z, v1.w);
  return r.s;
}

// ---------- prep: dst histogram + x->bf16 + W_ma fragment pack ----------
__global__ __launch_bounds__(256) void k_prep(
    const int* __restrict__ ei, const float* __restrict__ x,
    const float* __restrict__ Wma, int* __restrict__ cnt,
    short* __restrict__ xb, short* __restrict__ WtF) {
  const int i = blockIdx.x * 256 + threadIdx.x;      // grid covers 3.2M
  if (i < EE) atomicAdd(&cnt[ei[EE + i]], 1);
  if (i < NN * 64) xb[i] = f2bf(x[i]);
  if (i < 8192) {
    // WtF[((ks*4+cb)*64+lane)*8+j] = bf16(Wma[k][n]), k=ks*32+(lane>>4)*8+j,
    // n=cb*16+(lane&15)  -> B-frag ds_read_b128 at lane*16B, conflict-free
    int j = i & 7, lane = (i >> 3) & 63, cbks = i >> 9;
    int cb = cbks & 3, ks = cbks >> 2;
    int k = ks * 32 + (lane >> 4) * 8 + j;
    int n = cb * 16 + (lane & 15);
    WtF[i] = f2bf(Wma[k * 64 + n]);
  }
}

// ---------- scan: exclusive prefix over 50K counts ----------
__global__ __launch_bounds__(256) void k_scan(const int* __restrict__ cnt,
                                              int* __restrict__ head) {
  __shared__ int part[256];
  __shared__ int partx[256];
  const int t = threadIdx.x;
  const int chunk = (NN + 255) / 256;
  const int c0 = t * chunk;
  const int c1 = min(c0 + chunk, NN);
  int s = 0;
  for (int i = c0; i < c1; ++i) s += cnt[i];
  part[t] = s;
  __syncthreads();
  if (t == 0) {
    int r = 0;
    for (int i = 0; i < 256; ++i) { partx[i] = r; r += part[i]; }
  }
  __syncthreads();
  int run = partx[t];
  for (int i = c0; i < c1; ++i) { head[i] = run; run += cnt[i]; }
}

// ---------- scatter: sorted (src,dst) + e-row -> bf16 at sorted position ----------
__global__ __launch_bounds__(256) void k_scatter(
    const int* __restrict__ ei, const float* __restrict__ e,
    int* __restrict__ head, int* __restrict__ srcS, int* __restrict__ dstS,
    short* __restrict__ ebs, int* __restrict__ perm, int mode) {
  const int gid = blockIdx.x * 256 + threadIdx.x;    // 3.2M threads
  const int q = gid >> 2;                            // edge id
  const int l4 = gid & 3;
  const int lane = threadIdx.x & 63;
  int pos = 0;
  if (l4 == 0) {
    int d = ei[EE + q];
    pos = atomicAdd(&head[d], 1);
    srcS[pos] = ei[q];
    dstS[pos] = d;
    if (mode == 0) perm[pos] = q;
  }
  if (mode) {
    int posb = __shfl(pos, lane & ~3);
    const float* er = e + (size_t)q * 64 + l4 * 16;
    union { unsigned u[4]; uint4 v; } o0, o1;
    float4 v0 = *(const float4*)(er + 0);
    float4 v1 = *(const float4*)(er + 4);
    float4 v2 = *(const float4*)(er + 8);
    float4 v3 = *(const float4*)(er + 12);
    o0.u[0] = pack2(v0.x, v0.y); o0.u[1] = pack2(v0.z, v0.w);
    o0.u[2] = pack2(v1.x, v1.y); o0.u[3] = pack2(v1.z, v1.w);
    o1.u[0] = pack2(v2.x, v2.y); o1.u[1] = pack2(v2.z, v2.w);
    o1.u[2] = pack2(v3.x, v3.y); o1.u[3] = pack2(v3.z, v3.w);
    uint4* dst = (uint4*)(ebs + (size_t)posb * 64 + l4 * 16);
    dst[0] = o0.v; dst[1] = o1.v;
  }
}

// ---------- K1: msg_up = relu(attr1 @ W_mu + b_mu), rows = B*C ----------
__global__ __launch_bounds__(256) void k_msgup(
    const float* __restrict__ attr1, const float* __restrict__ Wmu,
    const float* __restrict__ bmu, float* __restrict__ msgup) {
  __shared__ float Wl[64 * 64];
  const int tid = threadIdx.x;
  for (int i = tid; i < 64 * 64; i += 256) Wl[i] = Wmu[i];
  __syncthreads();
  const int lane = tid & 63;
  const int row = blockIdx.x * 4 + (tid >> 6);
  float a = attr1[(size_t)row * 64 + lane];
  float acc = bmu[lane];
#pragma unroll 8
  for (int k = 0; k < 64; ++k)
    acc = fmaf(rl(a, k), Wl[k * 64 + lane], acc);
  msgup[(size_t)row * 64 + lane] = fmaxf(acc, 0.f);
}

// ---------- K2 (MFMA): agg_up = nc1 @ msg_up ----------
__global__ __launch_bounds__(256) void k_aggup(
    const float* __restrict__ nc1, const float* __restrict__ msgup,
    float* __restrict__ aggup) {
  constexpr int LDA = 136;
  __shared__ float Ncf[64 * CC];
  __shared__ short A[64 * LDA];
  __shared__ short Wt[64 * LDA];
  const int b = blockIdx.x >> 4;
  const int tile = blockIdx.x & 15;
  const int i0 = tile * 64;
  const int tid = threadIdx.x;
  const float* ncb = nc1 + ((size_t)b * NMAXX + i0) * CC;
  for (int idx = tid; idx < 64 * CC; idx += 256) {
    int r = idx / CC;
    Ncf[idx] = (i0 + r < NMAXX) ? ncb[idx] : 0.f;
  }
  for (int i = tid; i < 64 * LDA; i += 256) Wt[i] = 0;
  __syncthreads();
  for (int idx = tid; idx < CC * 64; idx += 256) {
    int c = idx >> 6, d = idx & 63;
    Wt[d * LDA + c] = f2bf(msgup[(size_t)b * CC * 64 + idx]);
  }
  __syncthreads();
  {
    const int row = tid >> 2, kp = tid & 3;
#pragma unroll
    for (int j = 0; j < 16; ++j) {
      int k = kp * 32 + 2 * j;
      unsigned u = 0;
      if (k < CC) {
        float2 v = *(const float2*)&Ncf[row * CC + k];
        u = pack2(v.x, v.y);
      }
      *(unsigned*)&A[row * LDA + k] = u;
    }
  }
  __syncthreads();
  const int lane = tid & 63;
  const int w = tid >> 6;
  const int m = lane & 15;
  const int koff = (lane >> 4) * 8;
  float4v acc[4];
#pragma unroll
  for (int cb = 0; cb < 4; ++cb) acc[cb] = (float4v)0.f;
#pragma unroll
  for (int ks = 0; ks < 4; ++ks) {
    short8 af = *(const short8*)&A[(w * 16 + m) * LDA + ks * 32 + koff];
#pragma unroll
    for (int cb = 0; cb < 4; ++cb) {
      short8 bf = *(const short8*)&Wt[(cb * 16 + m) * LDA + ks * 32 + koff];
      acc[cb] = __builtin_amdgcn_mfma_f32_16x16x32_bf16(af, bf, acc[cb], 0, 0, 0);
    }
  }
  const int rbase = (lane >> 4) * 4;
#pragma unroll
  for (int cb = 0; cb < 4; ++cb)
#pragma unroll
    for (int r = 0; r < 4; ++r) {
      int i = i0 + w * 16 + rbase + r;
      if (i < NMAXX)
        aggup[((size_t)b * NMAXX + i) * 64 + cb * 16 + m] = acc[cb][r];
    }
}

// ---------- K3 (MFMA): streaming edge MLP + segmented scatter ----------
// 128 edges/block (4 waves x 2 tiles). A-frags direct from global (no LDS A).
__global__ __launch_bounds__(256) void k_edge_mfma(
    const short* __restrict__ xb, const float* __restrict__ e,
    const short* __restrict__ ebs, const int* __restrict__ perm,
    const int* __restrict__ srcS, const int* __restrict__ dstSg,
    const short* __restrict__ WtF, const float* __restrict__ bma,
    float* __restrict__ agg, int mode) {
  __shared__ short WtL[8192];        // 16 KB, fragment-ordered
  __shared__ float Cs[4][16][68];    // 17.4 KB, per-wave C tile
  const int tid = threadIdx.x;
  {
    const uint4* s = (const uint4*)WtF;
    uint4* d = (uint4*)WtL;
#pragma unroll
    for (int it = 0; it < 4; ++it) d[it * 256 + tid] = s[it * 256 + tid];
  }
  __syncthreads();
  const int lane = tid & 63;
  const int wv = tid >> 6;
  const int m = lane & 15;
  const int koff = (lane >> 4) * 8;
  float bias[4];
#pragma unroll
  for (int cb = 0; cb < 4; ++cb) bias[cb] = bma[cb * 16 + m];
  const int p00 = blockIdx.x * 128;
#pragma unroll
  for (int half = 0; half < 2; ++half) {
    const int tb = p00 + (half * 4 + wv) * 16;   // tile base (sorted position)
    const int p = tb + m;
    const int src = srcS[p];
    short8 a0 = *(const short8*)(xb + (size_t)src * 64 + koff);
    short8 a1 = *(const short8*)(xb + (size_t)src * 64 + 32 + koff);
    short8 a2, a3;
    if (mode) {
      a2 = *(const short8*)(ebs + (size_t)p * 64 + koff);
      a3 = *(const short8*)(ebs + (size_t)p * 64 + 32 + koff);
    } else {
      const float* er = e + (size_t)perm[p] * 64;
      a2 = pack8(er + koff);
      a3 = pack8(er + 32 + koff);
    }
    float4v acc[4];
#pragma unroll
    for (int cb = 0; cb < 4; ++cb) acc[cb] = (float4v)0.f;
#pragma unroll
    for (int cb = 0; cb < 4; ++cb) {
      short8 b0 = *(const short8*)&WtL[((0 * 4 + cb) * 64 + lane) * 8];
      short8 b1 = *(const short8*)&WtL[((1 * 4 + cb) * 64 + lane) * 8];
      short8 b2 = *(const short8*)&WtL[((2 * 4 + cb) * 64 + lane) * 8];
      short8 b3 = *(const short8*)&WtL[((3 * 4 + cb) * 64 + lane) * 8];
      acc[cb] = __builtin_amdgcn_mfma_f32_16x16x32_bf16(a0, b0, acc[cb], 0, 0, 0);
      acc[cb] = __builtin_amdgcn_mfma_f32_16x16x32_bf16(a1, b1, acc[cb], 0, 0, 0);
      acc[cb] = __builtin_amdgcn_mfma_f32_16x16x32_bf16(a2, b2, acc[cb], 0, 0, 0);
      acc[cb] = __builtin_amdgcn_mfma_f32_16x16x32_bf16(a3, b3, acc[cb], 0, 0, 0);
    }
    const int rbase = (lane >> 4) * 4;
#pragma unroll
    for (int cb = 0; cb < 4; ++cb)
#pragma unroll
      for (int r = 0; r < 4; ++r)
        Cs[wv][rbase + r][cb * 16 + m] = fmaxf(acc[cb][r] + bias[cb], 0.f);
    // segmented reduce over 16 dst-sorted rows; lane owns one feature column
    int dprev = -1;
    float run = 0.f;
#pragma unroll
    for (int r = 0; r < 16; ++r) {
      int d = dstSg[tb + r];
      float v = Cs[wv][r][lane];
      if (d != dprev) {
        if (run != 0.f) atomicAdd(&agg[(size_t)dprev * 64 + lane], run);
        run = 0.f;
        dprev = d;
      }
      run += v;
    }
    if (run != 0.f) atomicAdd(&agg[(size_t)dprev * 64 + lane], run);
  }
}

// ---------- K4 (MFMA): fused epilogue ----------
__global__ __launch_bounds__(256) void k_final(
    const float* __restrict__ x, const float* __restrict__ agg,
    const float* __restrict__ aggup, const int* __restrict__ xidx,
    const float* __restrict__ eps1, const float* __restrict__ eps2,
    const float* __restrict__ Wua, const float* __restrict__ bua,
    const float* __restrict__ Wuu, const float* __restrict__ buu,
    const float* __restrict__ Wc, const float* __restrict__ bc,
    float* __restrict__ out) {
  constexpr int LD1 = 72;
  constexpr int LD3 = 136;
  __shared__ short Wt1[64 * LD1];
  __shared__ short Wt2[64 * LD1];
  __shared__ short Wt3[64 * LD3];
  __shared__ short A1[64 * LD1];
  __shared__ short A2[64 * LD1];
  __shared__ short O[64 * LD3];
  const int tid = threadIdx.x;
  for (int idx = tid; idx < 64 * 64; idx += 256) {
    int k = idx >> 6, d = idx & 63;
    Wt1[d * LD1 + k] = f2bf(Wua[idx]);
    Wt2[d * LD1 + k] = f2bf(Wuu[idx]);
  }
  for (int idx = tid; idx < 128 * 64; idx += 256) {
    int k = idx >> 6, d = idx & 63;
    Wt3[d * LD3 + k] = f2bf(Wc[idx]);
  }
  const float s1 = 1.f + eps1[0], s2 = 1.f + eps2[0];
  const int r0 = blockIdx.x * 64;
  {
    const int row = tid >> 2, kp = tid & 3;
    int g = r0 + row;
    if (g >= NN) g = NN - 1;
    const size_t xb_ = (size_t)g * 64 + kp * 16;
    const size_t ub = (size_t)xidx[g] * 64 + kp * 16;
#pragma unroll
    for (int j = 0; j < 4; ++j) {
      float4 xv = *(const float4*)&x[xb_ + j * 4];
      float4 av = *(const float4*)&agg[xb_ + j * 4];
      float4 uv = *(const float4*)&aggup[ub + j * 4];
      unsigned h1lo = pack2(av.x + s1 * xv.x, av.y + s1 * xv.y);
      unsigned h1hi = pack2(av.z + s1 * xv.z, av.w + s1 * xv.w);
      unsigned h2lo = pack2(uv.x + s2 * xv.x, uv.y + s2 * xv.y);
      unsigned h2hi = pack2(uv.z + s2 * xv.z, uv.w + s2 * xv.w);
      *(uint2*)&A1[row * LD1 + kp * 16 + j * 4] = make_uint2(h1lo, h1hi);
      *(uint2*)&A2[row * LD1 + kp * 16 + j * 4] = make_uint2(h2lo, h2hi);
    }
  }
  __syncthreads();
  const int lane = tid & 63;
  const int w = tid >> 6;
  const int m = lane & 15;
  const int koff = (lane >> 4) * 8;
  const int rbase = (lane >> 4) * 4;
  float4v acc1[4], acc2[4];
#pragma unroll
  for (int cb = 0; cb < 4; ++cb) { acc1[cb] = (float4v)0.f; acc2[cb] = (float4v)0.f; }
#pragma unroll
  for (int ks = 0; ks < 2; ++ks) {
    short8 a1 = *(const short8*)&A1[(w * 16 + m) * LD1 + ks * 32 + koff];
    short8 a2 = *(const short8*)&A2[(w * 16 + m) * LD1 + ks * 32 + koff];
#pragma unroll
    for (int cb = 0; cb < 4; ++cb) {
      short8 b1 = *(const short8*)&Wt1[(cb * 16 + m) * LD1 + ks * 32 + koff];
      short8 b2 = *(const short8*)&Wt2[(cb * 16 + m) * LD1 + ks * 32 + koff];
      acc1[cb] = __builtin_amdgcn_mfma_f32_16x16x32_bf16(a1, b1, acc1[cb], 0, 0, 0);
      acc2[cb] = __builtin_amdgcn_mfma_f32_16x16x32_bf16(a2, b2, acc2[cb], 0, 0, 0);
    }
  }
#pragma unroll
  for (int cb = 0; cb < 4; ++cb) {
    float bb1 = bua[cb * 16 + m];
    float bb2 = buu[cb * 16 + m];
#pragma unroll
    for (int r = 0; r < 4; ++r) {
      int rowL = w * 16 + rbase + r;
      O[rowL * LD3 + cb * 16 + m] = f2bf(fmaxf(acc1[cb][r] + bb1, 0.f));
      O[rowL * LD3 + 64 + cb * 16 + m] = f2bf(fmaxf(acc2[cb][r] + bb2, 0.f));
    }
  }
  __syncthreads();
  float4v acc3[4];
#pragma unroll
  for (int cb = 0; cb < 4; ++cb) acc3[cb] = (float4v)0.f;
#pragma unroll
  for (int ks = 0; ks < 4; ++ks) {
    short8 af = *(const short8*)&O[(w * 16 + m) * LD3 + ks * 32 + koff];
#pragma unroll
    for (int cb = 0; cb < 4; ++cb) {
      short8 bf = *(const short8*)&Wt3[(cb * 16 + m) * LD3 + ks * 32 + koff];
      acc3[cb] = __builtin_amdgcn_mfma_f32_16x16x32_bf16(af, bf, acc3[cb], 0, 0, 0);
    }
  }
#pragma unroll
  for (int cb = 0; cb < 4; ++cb) {
    float bb = bc[cb * 16 + m];
#pragma unroll
    for (int r = 0; r < 4; ++r) {
      int g = r0 + w * 16 + rbase + r;
      if (g < NN)
        out[(size_t)g * 64 + cb * 16 + m] = acc3[cb][r] + bb;
    }
  }
}

extern "C" void kernel_launch(void* const* d_in, const int* in_sizes, int n_in,
                              void* d_out, int out_size, void* d_ws, size_t ws_size,
                              hipStream_t stream) {
  const float* x     = (const float*)d_in[0];
  const float* e     = (const float*)d_in[1];
  const int*   ei    = (const int*)d_in[2];
  const float* attr1 = (const float*)d_in[3];
  const float* nc1   = (const float*)d_in[4];
  const int*   xidx  = (const int*)d_in[5];
  const float* eps1  = (const float*)d_in[6];
  const float* eps2  = (const float*)d_in[7];
  const float* Wma   = (const float*)d_in[8];
  const float* bma   = (const float*)d_in[9];
  const float* Wmu   = (const float*)d_in[10];
  const float* bmu   = (const float*)d_in[11];
  const float* Wua   = (const float*)d_in[12];
  const float* bua   = (const float*)d_in[13];
  const float* Wuu   = (const float*)d_in[14];
  const float* buu   = (const float*)d_in[15];
  const float* Wc    = (const float*)d_in[16];
  const float* bc    = (const float*)d_in[17];
  float* out = (float*)d_out;

  float* agg   = (float*)d_ws;                       // [N*64] f32
  int*   cnt   = (int*)(agg + (size_t)NN * 64);      // [N]  (memset with agg)
  float* aggup = (float*)(cnt + NN);                 // [N*64] f32
  float* msgup = aggup + (size_t)NN * 64;            // [B*C*64] f32
  short* xbuf  = (short*)(msgup + (size_t)BB * CC * 64);  // [N*64] bf16
  int*   head  = (int*)(xbuf + (size_t)NN * 64);     // [N]
  int*   srcS  = head + NN;                          // [E]
  int*   dstS  = srcS + EE;                          // [E]
  int*   perm  = dstS + EE;                          // [E] (fallback mode)
  short* WtF   = (short*)(perm + EE);                // [8192] bf16 frags
  short* ebs   = WtF + 8192;                         // [E*64] bf16 (mode 1)
  size_t need_full = (size_t)((char*)(ebs + (size_t)EE * 64) - (char*)d_ws);
  int mode = (ws_size >= need_full) ? 1 : 0;

  hipMemsetAsync(agg, 0, (size_t)NN * 64 * sizeof(float) + NN * sizeof(int),
                 stream);
  k_prep<<<dim3((NN * 64 + 255) / 256), dim3(256), 0, stream>>>(
      ei, x, Wma, cnt, xbuf, WtF);
  k_scan<<<dim3(1), dim3(256), 0, stream>>>(cnt, head);
  k_scatter<<<dim3(EE * 4 / 256), dim3(256), 0, stream>>>(
      ei, e, head, srcS, dstS, ebs, perm, mode);
  k_msgup<<<dim3(BB * CC / 4), dim3(256), 0, stream>>>(attr1, Wmu, bmu, msgup);
  k_aggup<<<dim3(BB * 16), dim3(256), 0, stream>>>(nc1, msgup, aggup);
  k_edge_mfma<<<dim3(EE / 128), dim3(256), 0, stream>>>(
      xbuf, e, ebs, perm, srcS, dstS, WtF, bma, agg, mode);
  k_final<<<dim3((NN + 63) / 64), dim3(256), 0, stream>>>(
      x, agg, aggup, xidx, eps1, eps2, Wua, bua, Wuu, buu, Wc, bc, out);
}

// Round 5
// 532.235 us; speedup vs baseline: 1.2271x; 1.2170x over previous
//
#include <hip/hip_runtime.h>

#define NN 50000
#define DD 64
#define EE 800000
#define BB 50
#define NMAXX 1000
#define CC 100

typedef short short8 __attribute__((ext_vector_type(8)));
typedef float float4v __attribute__((ext_vector_type(4)));

__device__ __forceinline__ float rl(float v, int l) {
  return __int_as_float(__builtin_amdgcn_readlane(__float_as_int(v), l));
}
__device__ __forceinline__ short f2bf(float f) {
  unsigned u = __float_as_uint(f);
  unsigned r = (u + 0x7fffu + ((u >> 16) & 1u)) >> 16;
  return (short)r;
}
__device__ __forceinline__ unsigned pack2(float a, float b) {
  return (unsigned)(unsigned short)f2bf(a) |
         ((unsigned)(unsigned short)f2bf(b) << 16);
}
__device__ __forceinline__ short8 pack8(const float* p) {
  union { unsigned u[4]; short8 s; } r;
  float4 v0 = *(const float4*)p;
  float4 v1 = *(const float4*)(p + 4);
  r.u[0] = pack2(v0.x, v0.y); r.u[1] = pack2(v0.z, v0.w);
  r.u[2] = pack2(v1.x, v1.y); r.u[3] = pack2(v1.z, v1.w);
  return r.s;
}

// B-fragment index for 16x16x32: frag[((ks*4+cb)*64+lane)*8+j] = W[k][n]
// k = ks*32 + (lane>>4)*8 + j, n = cb*16 + (lane&15)

// ---------- prep: histogram + x->bf16 + all W fragment packs ----------
__global__ __launch_bounds__(256) void k_prep(
    const int* __restrict__ ei, const float* __restrict__ x,
    const float* __restrict__ Wma, const float* __restrict__ Wua,
    const float* __restrict__ Wuu, const float* __restrict__ Wc,
    int* __restrict__ cnt, short* __restrict__ xb,
    short* __restrict__ WtF, short* __restrict__ WtF1,
    short* __restrict__ WtF2, short* __restrict__ WtF3) {
  const int i = blockIdx.x * 256 + threadIdx.x;   // grid covers NN*64 = 3.2M
  if (i < EE) atomicAdd(&cnt[ei[EE + i]], 1);
  if (i < NN * 64) xb[i] = f2bf(x[i]);
  if (i < 8192) {
    int j = i & 7, lane = (i >> 3) & 63, cbks = i >> 9;
    int cb = cbks & 3, ks = cbks >> 2;
    int k = ks * 32 + (lane >> 4) * 8 + j;
    int n = cb * 16 + (lane & 15);
    WtF[i]  = f2bf(Wma[k * 64 + n]);   // K=128
    WtF3[i] = f2bf(Wc[k * 64 + n]);    // K=128
    if (i < 4096) {                    // K=64 mats
      WtF1[i] = f2bf(Wua[k * 64 + n]);
      WtF2[i] = f2bf(Wuu[k * 64 + n]);
    }
  }
}

// ---------- 3-phase parallel exclusive scan over cnt[NN] ----------
#define CHUNK 196
__global__ __launch_bounds__(256) void k_scan1(const int* __restrict__ cnt,
                                               int* __restrict__ part) {
  __shared__ int s[256];
  const int t = threadIdx.x, b = blockIdx.x;
  const int gi = b * CHUNK + t;
  s[t] = (t < CHUNK && gi < NN) ? cnt[gi] : 0;
  __syncthreads();
#pragma unroll
  for (int off = 128; off; off >>= 1) {
    if (t < off) s[t] += s[t + off];
    __syncthreads();
  }
  if (t == 0) part[b] = s[0];
}
__global__ __launch_bounds__(256) void k_scan2(const int* __restrict__ part,
                                               int* __restrict__ partx) {
  if (threadIdx.x == 0) {
    int r = 0;
    for (int i = 0; i < 256; ++i) { partx[i] = r; r += part[i]; }
  }
}
__global__ __launch_bounds__(256) void k_scan3(const int* __restrict__ cnt,
                                               const int* __restrict__ partx,
                                               int* __restrict__ head) {
  __shared__ int s[256];
  const int t = threadIdx.x, b = blockIdx.x;
  const int gi = b * CHUNK + t;
  int v = (t < CHUNK && gi < NN) ? cnt[gi] : 0;
  s[t] = v;
  __syncthreads();
#pragma unroll
  for (int off = 1; off < 256; off <<= 1) {
    int tv = (t >= off) ? s[t - off] : 0;
    __syncthreads();
    s[t] += tv;
    __syncthreads();
  }
  if (t < CHUNK && gi < NN) head[gi] = partx[b] + s[t] - v;  // exclusive
}

// ---------- scatter: dst-sorted (src, dst, edge-id) ----------
__global__ __launch_bounds__(256) void k_scatter(
    const int* __restrict__ ei, int* __restrict__ head,
    int* __restrict__ srcS, int* __restrict__ dstS, int* __restrict__ perm) {
  const int q = blockIdx.x * 256 + threadIdx.x;
  int d = ei[EE + q];
  int pos = atomicAdd(&head[d], 1);
  srcS[pos] = ei[q];
  dstS[pos] = d;
  perm[pos] = q;
}

// ---------- K1: msgupT[b][d][c] = relu(attr1[b,c,:] @ W_mu + b_mu)[d], bf16 ----------
__global__ __launch_bounds__(256) void k_msgup(
    const float* __restrict__ attr1, const float* __restrict__ Wmu,
    const float* __restrict__ bmu, short* __restrict__ msgupT) {
  __shared__ float Wl[64 * 64];
  const int tid = threadIdx.x;
  for (int i = tid; i < 64 * 64; i += 256) Wl[i] = Wmu[i];
  __syncthreads();
  const int lane = tid & 63;
  const int row = blockIdx.x * 4 + (tid >> 6);   // b*100 + c
  float a = attr1[(size_t)row * 64 + lane];
  float acc = bmu[lane];
#pragma unroll 8
  for (int k = 0; k < 64; ++k)
    acc = fmaf(rl(a, k), Wl[k * 64 + lane], acc);
  const int b = row / 100, c = row - b * 100;
  msgupT[(size_t)b * 6400 + lane * 100 + c] = f2bf(fmaxf(acc, 0.f));
}

// ---------- K2 (MFMA): agg_up = nc1 @ msg_up ----------
__global__ __launch_bounds__(256) void k_aggup(
    const float* __restrict__ nc1, const short* __restrict__ msgupT,
    float* __restrict__ aggup) {
  constexpr int LDA = 136;
  __shared__ float Ncf[64 * CC];
  __shared__ short A[64 * LDA];
  __shared__ short Wt[64 * LDA];
  const int b = blockIdx.x >> 4;
  const int tile = blockIdx.x & 15;
  const int i0 = tile * 64;
  const int tid = threadIdx.x;
  const float* ncb = nc1 + ((size_t)b * NMAXX + i0) * CC;
  for (int idx = tid; idx < 64 * CC; idx += 256) {
    int r = idx / CC;
    Ncf[idx] = (i0 + r < NMAXX) ? ncb[idx] : 0.f;
  }
  // Wt rows: linear uint copy of msgupT[b] (64x100 bf16) + zero pad cols 100..127
  {
    const unsigned* src = (const unsigned*)(msgupT + (size_t)b * 6400);
    unsigned* dstw = (unsigned*)Wt;
    for (int i = tid; i < 64 * 50; i += 256) {
      int row = i / 50, cu = i - row * 50;
      dstw[row * 68 + cu] = src[i];
    }
    for (int i = tid; i < 64 * 14; i += 256) {
      int row = i / 14, cu = 50 + (i - row * 14);
      dstw[row * 68 + cu] = 0;
    }
  }
  __syncthreads();
  {
    const int row = tid >> 2, kp = tid & 3;
#pragma unroll
    for (int j = 0; j < 16; ++j) {
      int k = kp * 32 + 2 * j;
      unsigned u = 0;
      if (k < CC) {
        float2 v = *(const float2*)&Ncf[row * CC + k];
        u = pack2(v.x, v.y);
      }
      *(unsigned*)&A[row * LDA + k] = u;
    }
  }
  __syncthreads();
  const int lane = tid & 63;
  const int w = tid >> 6;
  const int m = lane & 15;
  const int koff = (lane >> 4) * 8;
  float4v acc[4];
#pragma unroll
  for (int cb = 0; cb < 4; ++cb) acc[cb] = (float4v)0.f;
#pragma unroll
  for (int ks = 0; ks < 4; ++ks) {
    short8 af = *(const short8*)&A[(w * 16 + m) * LDA + ks * 32 + koff];
#pragma unroll
    for (int cb = 0; cb < 4; ++cb) {
      short8 bf = *(const short8*)&Wt[(cb * 16 + m) * LDA + ks * 32 + koff];
      acc[cb] = __builtin_amdgcn_mfma_f32_16x16x32_bf16(af, bf, acc[cb], 0, 0, 0);
    }
  }
  const int rbase = (lane >> 4) * 4;
#pragma unroll
  for (int cb = 0; cb < 4; ++cb)
#pragma unroll
    for (int r = 0; r < 4; ++r) {
      int i = i0 + w * 16 + rbase + r;
      if (i < NMAXX)
        aggup[((size_t)b * NMAXX + i) * 64 + cb * 16 + m] = acc[cb][r];
    }
}

// ---------- K3 (MFMA): streaming edge MLP + segmented scatter ----------
__global__ __launch_bounds__(256) void k_edge_mfma(
    const short* __restrict__ xb, const float* __restrict__ e,
    const int* __restrict__ perm, const int* __restrict__ srcS,
    const int* __restrict__ dstSg, const short* __restrict__ WtF,
    const float* __restrict__ bma, float* __restrict__ agg) {
  __shared__ short WtL[8192];        // 16 KB fragment-ordered W_ma
  __shared__ float Cs[4][16][68];
  const int tid = threadIdx.x;
  {
    const uint4* s = (const uint4*)WtF;
    uint4* d = (uint4*)WtL;
#pragma unroll
    for (int it = 0; it < 4; ++it) d[it * 256 + tid] = s[it * 256 + tid];
  }
  __syncthreads();
  const int lane = tid & 63;
  const int wv = tid >> 6;
  const int m = lane & 15;
  const int koff = (lane >> 4) * 8;
  float bias[4];
#pragma unroll
  for (int cb = 0; cb < 4; ++cb) bias[cb] = bma[cb * 16 + m];
  const int p00 = blockIdx.x * 128;
#pragma unroll
  for (int half = 0; half < 2; ++half) {
    const int tb = p00 + (half * 4 + wv) * 16;
    const int p = tb + m;
    const int src = srcS[p];
    const int eid = perm[p];
    short8 a0 = *(const short8*)(xb + (size_t)src * 64 + koff);
    short8 a1 = *(const short8*)(xb + (size_t)src * 64 + 32 + koff);
    const float* er = e + (size_t)eid * 64;
    short8 a2 = pack8(er + koff);
    short8 a3 = pack8(er + 32 + koff);
    float4v acc[4];
#pragma unroll
    for (int cb = 0; cb < 4; ++cb) acc[cb] = (float4v)0.f;
#pragma unroll
    for (int cb = 0; cb < 4; ++cb) {
      short8 b0 = *(const short8*)&WtL[((0 * 4 + cb) * 64 + lane) * 8];
      short8 b1 = *(const short8*)&WtL[((1 * 4 + cb) * 64 + lane) * 8];
      short8 b2 = *(const short8*)&WtL[((2 * 4 + cb) * 64 + lane) * 8];
      short8 b3 = *(const short8*)&WtL[((3 * 4 + cb) * 64 + lane) * 8];
      acc[cb] = __builtin_amdgcn_mfma_f32_16x16x32_bf16(a0, b0, acc[cb], 0, 0, 0);
      acc[cb] = __builtin_amdgcn_mfma_f32_16x16x32_bf16(a1, b1, acc[cb], 0, 0, 0);
      acc[cb] = __builtin_amdgcn_mfma_f32_16x16x32_bf16(a2, b2, acc[cb], 0, 0, 0);
      acc[cb] = __builtin_amdgcn_mfma_f32_16x16x32_bf16(a3, b3, acc[cb], 0, 0, 0);
    }
    const int rbase = (lane >> 4) * 4;
#pragma unroll
    for (int cb = 0; cb < 4; ++cb)
#pragma unroll
      for (int r = 0; r < 4; ++r)
        Cs[wv][rbase + r][cb * 16 + m] = fmaxf(acc[cb][r] + bias[cb], 0.f);
    int dseg[16];
#pragma unroll
    for (int r = 0; r < 16; ++r) dseg[r] = dstSg[tb + r];
    int dprev = -1;
    float run = 0.f;
#pragma unroll
    for (int r = 0; r < 16; ++r) {
      float v = Cs[wv][r][lane];
      if (dseg[r] != dprev) {
        if (run != 0.f) atomicAdd(&agg[(size_t)dprev * 64 + lane], run);
        run = 0.f;
        dprev = dseg[r];
      }
      run += v;
    }
    if (run != 0.f) atomicAdd(&agg[(size_t)dprev * 64 + lane], run);
  }
}

// ---------- K4 (MFMA): fused epilogue, B-frags direct from global ----------
__global__ __launch_bounds__(256) void k_final(
    const float* __restrict__ x, const float* __restrict__ agg,
    const float* __restrict__ aggup, const int* __restrict__ xidx,
    const float* __restrict__ eps1, const float* __restrict__ eps2,
    const short* __restrict__ WtF1, const float* __restrict__ bua,
    const short* __restrict__ WtF2, const float* __restrict__ buu,
    const short* __restrict__ WtF3, const float* __restrict__ bc,
    float* __restrict__ out) {
  constexpr int LD1 = 72;
  constexpr int LD3 = 136;
  __shared__ short A1[64 * LD1];
  __shared__ short A2[64 * LD1];
  __shared__ short O[64 * LD3];
  const int tid = threadIdx.x;
  const float s1 = 1.f + eps1[0], s2 = 1.f + eps2[0];
  const int r0 = blockIdx.x * 64;
  {
    const int row = tid >> 2, kp = tid & 3;
    int g = r0 + row;
    if (g >= NN) g = NN - 1;
    const size_t xb_ = (size_t)g * 64 + kp * 16;
    const size_t ub = (size_t)xidx[g] * 64 + kp * 16;
#pragma unroll
    for (int j = 0; j < 4; ++j) {
      float4 xv = *(const float4*)&x[xb_ + j * 4];
      float4 av = *(const float4*)&agg[xb_ + j * 4];
      float4 uv = *(const float4*)&aggup[ub + j * 4];
      unsigned h1lo = pack2(av.x + s1 * xv.x, av.y + s1 * xv.y);
      unsigned h1hi = pack2(av.z + s1 * xv.z, av.w + s1 * xv.w);
      unsigned h2lo = pack2(uv.x + s2 * xv.x, uv.y + s2 * xv.y);
      unsigned h2hi = pack2(uv.z + s2 * xv.z, uv.w + s2 * xv.w);
      *(uint2*)&A1[row * LD1 + kp * 16 + j * 4] = make_uint2(h1lo, h1hi);
      *(uint2*)&A2[row * LD1 + kp * 16 + j * 4] = make_uint2(h2lo, h2hi);
    }
  }
  __syncthreads();
  const int lane = tid & 63;
  const int w = tid >> 6;
  const int m = lane & 15;
  const int koff = (lane >> 4) * 8;
  const int rbase = (lane >> 4) * 4;
  float4v acc1[4], acc2[4];
#pragma unroll
  for (int cb = 0; cb < 4; ++cb) { acc1[cb] = (float4v)0.f; acc2[cb] = (float4v)0.f; }
#pragma unroll
  for (int ks = 0; ks < 2; ++ks) {
    short8 a1 = *(const short8*)&A1[(w * 16 + m) * LD1 + ks * 32 + koff];
    short8 a2 = *(const short8*)&A2[(w * 16 + m) * LD1 + ks * 32 + koff];
#pragma unroll
    for (int cb = 0; cb < 4; ++cb) {
      short8 b1 = *(const short8*)&WtF1[((ks * 4 + cb) * 64 + lane) * 8];
      short8 b2 = *(const short8*)&WtF2[((ks * 4 + cb) * 64 + lane) * 8];
      acc1[cb] = __builtin_amdgcn_mfma_f32_16x16x32_bf16(a1, b1, acc1[cb], 0, 0, 0);
      acc2[cb] = __builtin_amdgcn_mfma_f32_16x16x32_bf16(a2, b2, acc2[cb], 0, 0, 0);
    }
  }
#pragma unroll
  for (int cb = 0; cb < 4; ++cb) {
    float bb1 = bua[cb * 16 + m];
    float bb2 = buu[cb * 16 + m];
#pragma unroll
    for (int r = 0; r < 4; ++r) {
      int rowL = w * 16 + rbase + r;
      O[rowL * LD3 + cb * 16 + m] = f2bf(fmaxf(acc1[cb][r] + bb1, 0.f));
      O[rowL * LD3 + 64 + cb * 16 + m] = f2bf(fmaxf(acc2[cb][r] + bb2, 0.f));
    }
  }
  __syncthreads();
  float4v acc3[4];
#pragma unroll
  for (int cb = 0; cb < 4; ++cb) acc3[cb] = (float4v)0.f;
#pragma unroll
  for (int ks = 0; ks < 4; ++ks) {
    short8 af = *(const short8*)&O[(w * 16 + m) * LD3 + ks * 32 + koff];
#pragma unroll
    for (int cb = 0; cb < 4; ++cb) {
      short8 bf = *(const short8*)&WtF3[((ks * 4 + cb) * 64 + lane) * 8];
      acc3[cb] = __builtin_amdgcn_mfma_f32_16x16x32_bf16(af, bf, acc3[cb], 0, 0, 0);
    }
  }
#pragma unroll
  for (int cb = 0; cb < 4; ++cb) {
    float bb = bc[cb * 16 + m];
#pragma unroll
    for (int r = 0; r < 4; ++r) {
      int g = r0 + w * 16 + rbase + r;
      if (g < NN)
        out[(size_t)g * 64 + cb * 16 + m] = acc3[cb][r] + bb;
    }
  }
}

extern "C" void kernel_launch(void* const* d_in, const int* in_sizes, int n_in,
                              void* d_out, int out_size, void* d_ws, size_t ws_size,
                              hipStream_t stream) {
  const float* x     = (const float*)d_in[0];
  const float* e     = (const float*)d_in[1];
  const int*   ei    = (const int*)d_in[2];
  const float* attr1 = (const float*)d_in[3];
  const float* nc1   = (const float*)d_in[4];
  const int*   xidx  = (const int*)d_in[5];
  const float* eps1  = (const float*)d_in[6];
  const float* eps2  = (const float*)d_in[7];
  const float* Wma   = (const float*)d_in[8];
  const float* bma   = (const float*)d_in[9];
  const float* Wmu   = (const float*)d_in[10];
  const float* bmu   = (const float*)d_in[11];
  const float* Wua   = (const float*)d_in[12];
  const float* bua   = (const float*)d_in[13];
  const float* Wuu   = (const float*)d_in[14];
  const float* buu   = (const float*)d_in[15];
  const float* Wc    = (const float*)d_in[16];
  const float* bc    = (const float*)d_in[17];
  float* out = (float*)d_out;

  float* agg    = (float*)d_ws;                      // [N*64] f32
  int*   cnt    = (int*)(agg + (size_t)NN * 64);     // [N] (memset with agg)
  float* aggup  = (float*)(cnt + NN);                // [N*64] f32
  short* msgupT = (short*)(aggup + (size_t)NN * 64); // [B*64*100] bf16
  short* xbuf   = msgupT + (size_t)BB * 6400;        // [N*64] bf16
  int*   head   = (int*)(xbuf + (size_t)NN * 64);    // [N]
  int*   part   = head + NN;                         // [256]
  int*   partx  = part + 256;                        // [256]
  int*   srcS   = partx + 256;                       // [E]
  int*   dstS   = srcS + EE;                         // [E]
  int*   perm   = dstS + EE;                         // [E]
  short* WtF    = (short*)(perm + EE);               // [8192]
  short* WtF1   = WtF + 8192;                        // [4096]
  short* WtF2   = WtF1 + 4096;                       // [4096]
  short* WtF3   = WtF2 + 4096;                       // [8192]

  hipMemsetAsync(agg, 0, (size_t)NN * 64 * sizeof(float) + NN * sizeof(int),
                 stream);
  k_prep<<<dim3((NN * 64 + 255) / 256), dim3(256), 0, stream>>>(
      ei, x, Wma, Wua, Wuu, Wc, cnt, xbuf, WtF, WtF1, WtF2, WtF3);
  k_scan1<<<dim3(256), dim3(256), 0, stream>>>(cnt, part);
  k_scan2<<<dim3(1), dim3(256), 0, stream>>>(part, partx);
  k_scan3<<<dim3(256), dim3(256), 0, stream>>>(cnt, partx, head);
  k_scatter<<<dim3(EE / 256), dim3(256), 0, stream>>>(ei, head, srcS, dstS, perm);
  k_msgup<<<dim3(BB * CC / 4), dim3(256), 0, stream>>>(attr1, Wmu, bmu, msgupT);
  k_aggup<<<dim3(BB * 16), dim3(256), 0, stream>>>(nc1, msgupT, aggup);
  k_edge_mfma<<<dim3(EE / 128), dim3(256), 0, stream>>>(
      xbuf, e, perm, srcS, dstS, WtF, bma, agg);
  k_final<<<dim3((NN + 63) / 64), dim3(256), 0, stream>>>(
      x, agg, aggup, xidx, eps1, eps2, WtF1, bua, WtF2, buu, WtF3, bc, out);
}